// Round 15
// baseline (40.962 us; speedup 1.0000x reference)
//
#include <hip/hip_runtime.h>
#include <math.h>

#define BATCH 4096
#define NROWS (2 * BATCH)      // 8192
#define D 128
#define DX 512

constexpr int NSPLIT = 8;
constexpr int NT = 8;               // 128-col tiles per split (1024 cols)
constexpr int SLOTS = NSPLIT * 2;   // row-partial slots (split x wc) = 16

// sqrt(2*log2(e)) — both Gram operands carry this, so dot == log2(exp(sim))
#define SCALE 1.698644f
// exp(sim_ii) = exp(|n_hat|^2 / T) = e^2 — constant diagonal, subtracted in k_rowlse
#define DIAG_E2 7.3890561f

// ws float offsets (every slot that is read is written every call; no atomics)
#define WS_PART   0                          // [NROWS][SLOTS] = 131072
#define WS_RECONP 131072                     // [512]
#define WS_ZRECP  (WS_RECONP + 512)          // [256]
#define WS_POSP   (WS_ZRECP + 256)           // [256]
#define WS_LSEP   (WS_POSP + 256)            // [64]
#define WS_NBF8   (WS_LSEP + 64)             // fp8[16][NROWS][8] chunk-transposed (1 MB)

typedef float f32x16 __attribute__((ext_vector_type(16)));
typedef long long i64;
typedef unsigned char u8;
typedef unsigned short u16;

__device__ __forceinline__ float wave_reduce(float v) {
    #pragma unroll
    for (int o = 32; o > 0; o >>= 1) v += __shfl_xor(v, o);
    return v;
}

// one wave per (i, i+B) pair: norms, chunk-transposed scaled-fp8 rows,
// zrecon & positives partials (f32 exact)
__global__ __launch_bounds__(256) void k_prep(const float* __restrict__ rep,
                                              float* __restrict__ ws) {
    const int w = threadIdx.x >> 6, l = threadIdx.x & 63;
    const int wg = blockIdx.x * 4 + w;          // 0..1023
    u8* nbf8 = (u8*)(ws + WS_NBF8);
    const int chunk = l >> 2, el = (l & 3) * 2; // lane's 2 elems live here
    float zacc = 0.f, pacc = 0.f;
    #pragma unroll
    for (int p = 0; p < 4; ++p) {
        const int i = wg + p * 1024;            // 0..4095
        float2 a = *reinterpret_cast<const float2*>(rep + i * D + l * 2);
        float2 b = *reinterpret_cast<const float2*>(rep + (i + BATCH) * D + l * 2);
        float dx = a.x - b.x, dy = a.y - b.y;
        float sa  = wave_reduce(a.x * a.x + a.y * a.y);
        float sb  = wave_reduce(b.x * b.x + b.y * b.y);
        float sab = wave_reduce(a.x * b.x + a.y * b.y);
        float sd  = wave_reduce(dx * dx + dy * dy);
        float ia = 1.0f / (sqrtf(sa) + 1e-8f);
        float ib = 1.0f / (sqrtf(sb) + 1e-8f);
        zacc += sd;
        pacc += sab * ia * ib;
        int pka = __builtin_amdgcn_cvt_pk_fp8_f32(a.x * ia * SCALE,
                                                  a.y * ia * SCALE, 0, false);
        int pkb = __builtin_amdgcn_cvt_pk_fp8_f32(b.x * ib * SCALE,
                                                  b.y * ib * SCALE, 0, false);
        *reinterpret_cast<u16*>(
            nbf8 + ((size_t)chunk * NROWS + i) * 8 + el) = (u16)pka;
        *reinterpret_cast<u16*>(
            nbf8 + ((size_t)chunk * NROWS + i + BATCH) * 8 + el) = (u16)pkb;
    }
    __shared__ float shz[4], shp[4];
    if (l == 0) { shz[w] = zacc; shp[w] = pacc; }
    __syncthreads();
    if (threadIdx.x == 0) {
        ws[WS_ZRECP + blockIdx.x] = shz[0] + shz[1] + shz[2] + shz[3];
        ws[WS_POSP + blockIdx.x] = 4.0f * (shp[0] + shp[1] + shp[2] + shp[3]);
    }
}

// fp8 MFMA Gram + fused exp2-rowsum + fused xrecon-MSE partial.
// No LDS / no barriers. 2x2 waves per 128x128 tile; each wave owns a 64x64
// quadrant (4 independent MFMA chains). B fragments AND xrecon pairs are
// register double-buffered; NT loop fully 2-step unrolled (static buffer
// names, rule-#20 safe). No diagonal masking: the diagonal contributes the
// constant e^2 per row, subtracted once in k_rowlse (verified in R14).
__global__ __launch_bounds__(256, 2) void k_lse(const float4* __restrict__ xr,
                                                const float4* __restrict__ xo,
                                                float* __restrict__ ws) {
    const u8* __restrict__ nbf8 = (const u8*)(ws + WS_NBF8);
    const int tid = threadIdx.x;
    const int w = tid >> 6, l = tid & 63;
    const int wr = w >> 1, wc = w & 1;
    const int rblk = blockIdx.x;                 // 0..63
    const int split = blockIdx.y;                // 0..7
    const int R0 = rblk * 128;
    const int fid = rblk + 64 * split;           // 0..511

    // ---- A fragments: 2 row-blocks of 32, registers, reused across tiles
    i64 afrag[2][8];
    #pragma unroll
    for (int rb = 0; rb < 2; ++rb) {
        const int lr = R0 + wr * 64 + rb * 32 + (l & 31);
        #pragma unroll
        for (int k = 0; k < 8; ++k) {
            const int c = 2 * k + (l >> 5);
            afrag[rb][k] = *reinterpret_cast<const i64*>(
                nbf8 + ((size_t)c * NROWS + lr) * 8);
        }
    }

    i64 bufA[16], bufB[16];
    float4 raA, rbA, raB, rbB;
    float sumexp[2][16] = {};
    float racc = 0.f;

    auto loadB = [&](i64 (&buf)[16], int t) {
        const int lc = split * (NT * 128) + t * 128 + wc * 64 + (l & 31);
        #pragma unroll
        for (int k = 0; k < 8; ++k) {
            const int c = 2 * k + (l >> 5);
            const u8* base = nbf8 + (size_t)c * NROWS * 8;
            buf[2 * k]     = *reinterpret_cast<const i64*>(base + (size_t)lc * 8);
            buf[2 * k + 1] = *reinterpret_cast<const i64*>(base + (size_t)(lc + 32) * 8);
        }
    };

    auto tile = [&](i64 (&buf)[16], float4 ra, float4 rb2) {
        f32x16 acc[2][2] = {};
        #pragma unroll
        for (int k = 0; k < 8; ++k) {
            acc[0][0] = __builtin_amdgcn_mfma_f32_32x32x16_fp8_fp8(
                afrag[0][k], buf[2 * k], acc[0][0], 0, 0, 0);
            acc[0][1] = __builtin_amdgcn_mfma_f32_32x32x16_fp8_fp8(
                afrag[0][k], buf[2 * k + 1], acc[0][1], 0, 0, 0);
            acc[1][0] = __builtin_amdgcn_mfma_f32_32x32x16_fp8_fp8(
                afrag[1][k], buf[2 * k], acc[1][0], 0, 0, 0);
            acc[1][1] = __builtin_amdgcn_mfma_f32_32x32x16_fp8_fp8(
                afrag[1][k], buf[2 * k + 1], acc[1][1], 0, 0, 0);
        }
        {
            float dx = ra.x - rb2.x, dy = ra.y - rb2.y;
            float dz = ra.z - rb2.z, dw2 = ra.w - rb2.w;
            racc += dx * dx + dy * dy + dz * dz + dw2 * dw2;
        }
        // acc == sim*log2(e) by operand scaling → exp(sim) = exp2(acc)
        #pragma unroll
        for (int rb = 0; rb < 2; ++rb) {
            #pragma unroll
            for (int cb = 0; cb < 2; ++cb) {
                #pragma unroll
                for (int r = 0; r < 16; ++r)
                    sumexp[rb][r] += __builtin_amdgcn_exp2f(acc[rb][cb][r]);
            }
        }
    };

    // ---- prologue: tile 0 buffers
    loadB(bufA, 0);
    {
        const int ri = fid * 2048 + tid;
        raA = xr[ri]; rbA = xo[ri];
    }

    // ---- 2-step unrolled main loop (all buffer refs static)
    #pragma unroll
    for (int tt = 0; tt < NT; tt += 2) {
        if (tt + 1 < NT) {
            loadB(bufB, tt + 1);
            const int ri = fid * 2048 + (tt + 1) * 256 + tid;
            raB = xr[ri]; rbB = xo[ri];
        }
        tile(bufA, raA, rbA);
        if (tt + 2 < NT) {
            loadB(bufA, tt + 2);
            const int ri = fid * 2048 + (tt + 2) * 256 + tid;
            raA = xr[ri]; rbA = xo[ri];
        }
        if (tt + 1 < NT) tile(bufB, raB, rbB);
    }

    // reduce over the 32 column-lanes; lanes 0 and 32 hold row sums
    #pragma unroll
    for (int rb = 0; rb < 2; ++rb) {
        #pragma unroll
        for (int r = 0; r < 16; ++r) {
            float v = sumexp[rb][r];
            #pragma unroll
            for (int m = 1; m <= 16; m <<= 1) v += __shfl_xor(v, m);
            sumexp[rb][r] = v;
        }
    }
    if ((l & 31) == 0) {
        #pragma unroll
        for (int rb = 0; rb < 2; ++rb) {
            #pragma unroll
            for (int r = 0; r < 16; ++r) {
                const int row = R0 + wr * 64 + rb * 32
                              + (r & 3) + 8 * (r >> 2) + 4 * (l >> 5);
                ws[WS_PART + row * SLOTS + split * 2 + wc] = sumexp[rb][r];
            }
        }
    }

    // recon partial for this block
    racc = wave_reduce(racc);
    __shared__ float shr[4];
    if (l == 0) shr[w] = racc;
    __syncthreads();
    if (tid == 0) ws[WS_RECONP + fid] = shr[0] + shr[1] + shr[2] + shr[3];
}

// per row-block q (128 rows): sum the 16 slots per row, subtract the constant
// diagonal term e^2, log, block partial
__global__ __launch_bounds__(256) void k_rowlse(float* __restrict__ ws) {
    const int q = blockIdx.x, tid = threadIdx.x;
    const int j = tid & 127, h = tid >> 7;       // 2 threads per row
    const int row = q * 128 + j;
    float s = 0.f;
    #pragma unroll
    for (int ss = 0; ss < SLOTS / 2; ++ss)
        s += ws[WS_PART + row * SLOTS + 2 * ss + h];
    __shared__ float red[128];
    if (h) red[j] = s;
    __syncthreads();
    float lg = 0.f;
    if (!h) lg = logf(s + red[j] - DIAG_E2);
    lg = wave_reduce(lg);
    __shared__ float sh[4];
    const int w = tid >> 6, l = tid & 63;
    if (l == 0) sh[w] = lg;
    __syncthreads();
    if (tid == 0) ws[WS_LSEP + q] = sh[0] + sh[1] + sh[2] + sh[3];
}

__global__ __launch_bounds__(256) void k_combine(const float* __restrict__ ws,
                                                 float* __restrict__ out) {
    const int tid = threadIdx.x;
    float lacc = (tid < 64) ? ws[WS_LSEP + tid] : 0.f;
    float racc = ws[WS_RECONP + tid] + ws[WS_RECONP + 256 + tid];
    float zacc = ws[WS_ZRECP + tid];
    float pacc = ws[WS_POSP + tid];

    lacc = wave_reduce(lacc);
    racc = wave_reduce(racc);
    zacc = wave_reduce(zacc);
    pacc = wave_reduce(pacc);

    __shared__ float sh[4][4];
    const int w = tid >> 6, l = tid & 63;
    if (l == 0) { sh[0][w] = lacc; sh[1][w] = racc; sh[2][w] = zacc; sh[3][w] = pacc; }
    __syncthreads();
    if (tid == 0) {
        float lse = sh[0][0] + sh[0][1] + sh[0][2] + sh[0][3];
        float rec = (sh[1][0] + sh[1][1] + sh[1][2] + sh[1][3]) / (float)(NROWS * DX);
        float zre = (sh[2][0] + sh[2][1] + sh[2][2] + sh[2][3]) / (float)(BATCH * D);
        float pos = sh[3][0] + sh[3][1] + sh[3][2] + sh[3][3];
        float closs = (lse - pos) / (float)NROWS;
        out[0] = rec + closs + zre;
        out[1] = closs;
        out[2] = rec;
        out[3] = zre;
    }
}

extern "C" void kernel_launch(void* const* d_in, const int* in_sizes, int n_in,
                              void* d_out, int out_size, void* d_ws, size_t ws_size,
                              hipStream_t stream) {
    const float* rep = (const float*)d_in[0];
    const float4* xr = (const float4*)d_in[1];
    const float4* xo = (const float4*)d_in[2];
    float* out = (float*)d_out;
    float* ws = (float*)d_ws;

    k_prep<<<256, 256, 0, stream>>>(rep, ws);
    dim3 grid(64, NSPLIT);
    k_lse<<<grid, 256, 0, stream>>>(xr, xo, ws);
    k_rowlse<<<64, 256, 0, stream>>>(ws);
    k_combine<<<1, 256, 0, stream>>>(ws, out);
}

// Round 16
// 33.204 us; speedup vs baseline: 1.2337x; 1.2337x over previous
//
#include <hip/hip_runtime.h>
#include <math.h>

#define BATCH 4096
#define NROWS (2 * BATCH)      // 8192
#define D 128
#define DX 512

constexpr int NSPLIT = 8;
constexpr int NT = 8;               // 128-col tiles per split (1024 cols)
constexpr int SLOTS = NSPLIT * 2;   // row-partial slots (split x wc) = 16

// sqrt(2*log2(e)) — both Gram operands carry this, so dot == log2(exp(sim))
#define SCALE 1.698644f

// ws float offsets (every slot that is read is written every call; no atomics)
#define WS_PART   0                          // [NROWS][SLOTS] = 131072
#define WS_RECONP 131072                     // [512]
#define WS_ZRECP  (WS_RECONP + 512)          // [256]
#define WS_POSP   (WS_ZRECP + 256)           // [256]
#define WS_LSEP   (WS_POSP + 256)            // [64]
#define WS_NBF8   (WS_LSEP + 64)             // fp8[16][NROWS][8] chunk-transposed (1 MB)

typedef float f32x16 __attribute__((ext_vector_type(16)));
typedef long long i64;
typedef unsigned char u8;
typedef unsigned short u16;

__device__ __forceinline__ float wave_reduce(float v) {
    #pragma unroll
    for (int o = 32; o > 0; o >>= 1) v += __shfl_xor(v, o);
    return v;
}

// one wave per (i, i+B) pair: norms, chunk-transposed scaled-fp8 rows,
// zrecon & positives partials (f32 exact)
__global__ __launch_bounds__(256) void k_prep(const float* __restrict__ rep,
                                              float* __restrict__ ws) {
    const int w = threadIdx.x >> 6, l = threadIdx.x & 63;
    const int wg = blockIdx.x * 4 + w;          // 0..1023
    u8* nbf8 = (u8*)(ws + WS_NBF8);
    const int chunk = l >> 2, el = (l & 3) * 2; // lane's 2 elems live here
    float zacc = 0.f, pacc = 0.f;
    #pragma unroll
    for (int p = 0; p < 4; ++p) {
        const int i = wg + p * 1024;            // 0..4095
        float2 a = *reinterpret_cast<const float2*>(rep + i * D + l * 2);
        float2 b = *reinterpret_cast<const float2*>(rep + (i + BATCH) * D + l * 2);
        float dx = a.x - b.x, dy = a.y - b.y;
        float sa  = wave_reduce(a.x * a.x + a.y * a.y);
        float sb  = wave_reduce(b.x * b.x + b.y * b.y);
        float sab = wave_reduce(a.x * b.x + a.y * b.y);
        float sd  = wave_reduce(dx * dx + dy * dy);
        float ia = 1.0f / (sqrtf(sa) + 1e-8f);
        float ib = 1.0f / (sqrtf(sb) + 1e-8f);
        zacc += sd;
        pacc += sab * ia * ib;
        int pka = __builtin_amdgcn_cvt_pk_fp8_f32(a.x * ia * SCALE,
                                                  a.y * ia * SCALE, 0, false);
        int pkb = __builtin_amdgcn_cvt_pk_fp8_f32(b.x * ib * SCALE,
                                                  b.y * ib * SCALE, 0, false);
        *reinterpret_cast<u16*>(
            nbf8 + ((size_t)chunk * NROWS + i) * 8 + el) = (u16)pka;
        *reinterpret_cast<u16*>(
            nbf8 + ((size_t)chunk * NROWS + i + BATCH) * 8 + el) = (u16)pkb;
    }
    __shared__ float shz[4], shp[4];
    if (l == 0) { shz[w] = zacc; shp[w] = pacc; }
    __syncthreads();
    if (threadIdx.x == 0) {
        ws[WS_ZRECP + blockIdx.x] = shz[0] + shz[1] + shz[2] + shz[3];
        ws[WS_POSP + blockIdx.x] = 4.0f * (shp[0] + shp[1] + shp[2] + shp[3]);
    }
}

// fp8 MFMA Gram + fused exp2-rowsum + fused xrecon-MSE partial.
// No LDS / no barriers. 2x2 waves per 128x128 tile, each wave owns a 64x64
// quadrant (4 independent MFMA chains). B fragments AND xrecon pairs are
// register double-buffered: next tile's loads issue before this tile's
// compute, so the per-tile L2/HBM latency is fully hidden. The NT loop is
// 2-step unrolled so all buffer indices are compile-time constants.
__global__ __launch_bounds__(256, 2) void k_lse(const float4* __restrict__ xr,
                                                const float4* __restrict__ xo,
                                                float* __restrict__ ws) {
    const u8* __restrict__ nbf8 = (const u8*)(ws + WS_NBF8);
    const int tid = threadIdx.x;
    const int w = tid >> 6, l = tid & 63;
    const int wr = w >> 1, wc = w & 1;
    const int rblk = blockIdx.x;                 // 0..63
    const int split = blockIdx.y;                // 0..7
    const int R0 = rblk * 128;
    const int fid = rblk + 64 * split;           // 0..511

    // ---- A fragments: 2 row-blocks of 32, registers, reused across tiles
    i64 afrag[2][8];
    #pragma unroll
    for (int rb = 0; rb < 2; ++rb) {
        const int lr = R0 + wr * 64 + rb * 32 + (l & 31);
        #pragma unroll
        for (int s = 0; s < 8; ++s) {
            const int c = 2 * s + (l >> 5);
            afrag[rb][s] = *reinterpret_cast<const i64*>(
                nbf8 + ((size_t)c * NROWS + lr) * 8);
        }
    }

    i64 bufA[16], bufB[16];
    float4 raA, rbA, raB, rbB;
    float sumexp[2][16] = {};
    float racc = 0.f;

    auto loadB = [&](i64 (&buf)[16], int t) {
        const int lc = split * (NT * 128) + t * 128 + wc * 64 + (l & 31);
        #pragma unroll
        for (int s = 0; s < 8; ++s) {
            const int c = 2 * s + (l >> 5);
            const u8* base = nbf8 + (size_t)c * NROWS * 8;
            buf[2 * s]     = *reinterpret_cast<const i64*>(base + (size_t)lc * 8);
            buf[2 * s + 1] = *reinterpret_cast<const i64*>(base + (size_t)(lc + 32) * 8);
        }
    };

    auto tile = [&](i64 (&buf)[16], int t, float4 ra, float4 rb2) {
        const int C0 = split * (NT * 128) + t * 128;
        const bool diagt = (C0 == R0);
        f32x16 acc[2][2] = {};
        #pragma unroll
        for (int s = 0; s < 8; ++s) {
            acc[0][0] = __builtin_amdgcn_mfma_f32_32x32x16_fp8_fp8(
                afrag[0][s], buf[2 * s], acc[0][0], 0, 0, 0);
            acc[0][1] = __builtin_amdgcn_mfma_f32_32x32x16_fp8_fp8(
                afrag[0][s], buf[2 * s + 1], acc[0][1], 0, 0, 0);
            acc[1][0] = __builtin_amdgcn_mfma_f32_32x32x16_fp8_fp8(
                afrag[1][s], buf[2 * s], acc[1][0], 0, 0, 0);
            acc[1][1] = __builtin_amdgcn_mfma_f32_32x32x16_fp8_fp8(
                afrag[1][s], buf[2 * s + 1], acc[1][1], 0, 0, 0);
        }
        {
            float dx = ra.x - rb2.x, dy = ra.y - rb2.y;
            float dz = ra.z - rb2.z, dw2 = ra.w - rb2.w;
            racc += dx * dx + dy * dy + dz * dz + dw2 * dw2;
        }
        // acc == sim*log2(e) by operand scaling → exp(sim) = exp2(acc)
        #pragma unroll
        for (int rb = 0; rb < 2; ++rb) {
            #pragma unroll
            for (int cb = 0; cb < 2; ++cb) {
                const bool dmask = diagt && ((2 * wr + rb) == (2 * wc + cb));
                #pragma unroll
                for (int r = 0; r < 16; ++r) {
                    float e = __builtin_amdgcn_exp2f(acc[rb][cb][r]);
                    if (dmask) {
                        const int rrow = (r & 3) + 8 * (r >> 2) + 4 * (l >> 5);
                        if (rrow == (l & 31)) e = 0.0f;
                    }
                    sumexp[rb][r] += e;
                }
            }
        }
    };

    // ---- prologue: tile 0 buffers
    loadB(bufA, 0);
    {
        const int ri = fid * 2048 + tid;
        raA = xr[ri]; rbA = xo[ri];
    }

    // ---- 2-step unrolled main loop (all buffer refs static)
    #pragma unroll
    for (int tt = 0; tt < NT; tt += 2) {
        if (tt + 1 < NT) {
            loadB(bufB, tt + 1);
            const int ri = fid * 2048 + (tt + 1) * 256 + tid;
            raB = xr[ri]; rbB = xo[ri];
        }
        tile(bufA, tt, raA, rbA);
        if (tt + 2 < NT) {
            loadB(bufA, tt + 2);
            const int ri = fid * 2048 + (tt + 2) * 256 + tid;
            raA = xr[ri]; rbA = xo[ri];
        }
        if (tt + 1 < NT) tile(bufB, tt + 1, raB, rbB);
    }

    // reduce over the 32 column-lanes; lanes 0 and 32 hold row sums
    #pragma unroll
    for (int rb = 0; rb < 2; ++rb) {
        #pragma unroll
        for (int r = 0; r < 16; ++r) {
            float v = sumexp[rb][r];
            #pragma unroll
            for (int m = 1; m <= 16; m <<= 1) v += __shfl_xor(v, m);
            sumexp[rb][r] = v;
        }
    }
    if ((l & 31) == 0) {
        #pragma unroll
        for (int rb = 0; rb < 2; ++rb) {
            #pragma unroll
            for (int r = 0; r < 16; ++r) {
                const int row = R0 + wr * 64 + rb * 32
                              + (r & 3) + 8 * (r >> 2) + 4 * (l >> 5);
                ws[WS_PART + row * SLOTS + split * 2 + wc] = sumexp[rb][r];
            }
        }
    }

    // recon partial for this block
    racc = wave_reduce(racc);
    __shared__ float shr[4];
    if (l == 0) shr[w] = racc;
    __syncthreads();
    if (tid == 0) ws[WS_RECONP + fid] = shr[0] + shr[1] + shr[2] + shr[3];
}

// per row-block q (128 rows): sum the 16 slots per row, log, block partial
__global__ __launch_bounds__(256) void k_rowlse(float* __restrict__ ws) {
    const int q = blockIdx.x, tid = threadIdx.x;
    const int j = tid & 127, h = tid >> 7;       // 2 threads per row
    const int row = q * 128 + j;
    float s = 0.f;
    #pragma unroll
    for (int ss = 0; ss < SLOTS / 2; ++ss)
        s += ws[WS_PART + row * SLOTS + 2 * ss + h];
    __shared__ float red[128];
    if (h) red[j] = s;
    __syncthreads();
    float lg = 0.f;
    if (!h) lg = logf(s + red[j]);
    lg = wave_reduce(lg);
    __shared__ float sh[4];
    const int w = tid >> 6, l = tid & 63;
    if (l == 0) sh[w] = lg;
    __syncthreads();
    if (tid == 0) ws[WS_LSEP + q] = sh[0] + sh[1] + sh[2] + sh[3];
}

__global__ __launch_bounds__(256) void k_combine(const float* __restrict__ ws,
                                                 float* __restrict__ out) {
    const int tid = threadIdx.x;
    float lacc = (tid < 64) ? ws[WS_LSEP + tid] : 0.f;
    float racc = ws[WS_RECONP + tid] + ws[WS_RECONP + 256 + tid];
    float zacc = ws[WS_ZRECP + tid];
    float pacc = ws[WS_POSP + tid];

    lacc = wave_reduce(lacc);
    racc = wave_reduce(racc);
    zacc = wave_reduce(zacc);
    pacc = wave_reduce(pacc);

    __shared__ float sh[4][4];
    const int w = tid >> 6, l = tid & 63;
    if (l == 0) { sh[0][w] = lacc; sh[1][w] = racc; sh[2][w] = zacc; sh[3][w] = pacc; }
    __syncthreads();
    if (tid == 0) {
        float lse = sh[0][0] + sh[0][1] + sh[0][2] + sh[0][3];
        float rec = (sh[1][0] + sh[1][1] + sh[1][2] + sh[1][3]) / (float)(NROWS * DX);
        float zre = (sh[2][0] + sh[2][1] + sh[2][2] + sh[2][3]) / (float)(BATCH * D);
        float pos = sh[3][0] + sh[3][1] + sh[3][2] + sh[3][3];
        float closs = (lse - pos) / (float)NROWS;
        out[0] = rec + closs + zre;
        out[1] = closs;
        out[2] = rec;
        out[3] = zre;
    }
}

extern "C" void kernel_launch(void* const* d_in, const int* in_sizes, int n_in,
                              void* d_out, int out_size, void* d_ws, size_t ws_size,
                              hipStream_t stream) {
    const float* rep = (const float*)d_in[0];
    const float4* xr = (const float4*)d_in[1];
    const float4* xo = (const float4*)d_in[2];
    float* out = (float*)d_out;
    float* ws = (float*)d_ws;

    k_prep<<<256, 256, 0, stream>>>(rep, ws);
    dim3 grid(64, NSPLIT);
    k_lse<<<grid, 256, 0, stream>>>(xr, xo, ws);
    k_rowlse<<<64, 256, 0, stream>>>(ws);
    k_combine<<<1, 256, 0, stream>>>(ws, out);
}